// Round 1
// baseline (277.226 us; speedup 1.0000x reference)
//
#include <hip/hip_runtime.h>

#define KS 3
#define OUTC 3
#define FEATC 6
#define PATCH (FEATC * KS * KS)  // 54

// out[b,o,h,w] = sum_{c,dy,dx} feat[b,c,h+dy-1,w+dx-1] * km[b, o*54 + c*9 + dy*3 + dx, h, w]
// (zero padding outside feat bounds)
//
// Each thread computes 4 consecutive output pixels (w0..w0+3) for all 3 output
// channels. kernel_map is streamed with float4 loads (fully coalesced, read
// exactly once); feat rows are loaded as one aligned float4 + 2 boundary
// scalars and are L2/L3 resident (feat is only 25 MB total).
__global__ __launch_bounds__(256) void supersample_kernel(
    const float* __restrict__ feat,
    const float* __restrict__ km,
    float* __restrict__ out,
    int B, int H, int W)
{
    const int Wq = W >> 2;                 // pixels-per-thread groups along W
    const int total = B * H * Wq;
    int idx = blockIdx.x * blockDim.x + threadIdx.x;
    if (idx >= total) return;

    const int wq  = idx % Wq;
    const int tmp = idx / Wq;
    const int h   = tmp % H;
    const int b   = tmp / H;
    const int w0  = wq << 2;

    const size_t HW = (size_t)H * (size_t)W;
    const float* featb = feat + (size_t)b * FEATC * HW;
    const float* kmb   = km   + (size_t)b * OUTC * PATCH * HW;
    float*       outb  = out  + (size_t)b * OUTC * HW;

    float4 acc[OUTC];
#pragma unroll
    for (int o = 0; o < OUTC; ++o) acc[o] = make_float4(0.f, 0.f, 0.f, 0.f);

#pragma unroll
    for (int c = 0; c < FEATC; ++c) {
        // Load 3 feat row windows of 6 values: r[ky][j] = feat[c, h+ky-1, w0-1+j]
        float r[3][6];
#pragma unroll
        for (int ky = 0; ky < 3; ++ky) {
            const int hy = h + ky - 1;
            if (hy < 0 || hy >= H) {
#pragma unroll
                for (int j = 0; j < 6; ++j) r[ky][j] = 0.f;
            } else {
                const float* row = featb + (size_t)c * HW + (size_t)hy * W;
                // w0 is a multiple of 4 -> aligned float4
                const float4 mid = *reinterpret_cast<const float4*>(row + w0);
                r[ky][1] = mid.x; r[ky][2] = mid.y; r[ky][3] = mid.z; r[ky][4] = mid.w;
                r[ky][0] = (w0 > 0)     ? row[w0 - 1] : 0.f;
                r[ky][5] = (w0 + 4 < W) ? row[w0 + 4] : 0.f;
            }
        }

        // Stream kernel_map: for each (o, dy, dx) one coalesced float4 load + FMA
#pragma unroll
        for (int o = 0; o < OUTC; ++o) {
            const float* kmc = kmb + ((size_t)(o * PATCH + c * KS * KS)) * HW
                                   + (size_t)h * W + w0;
#pragma unroll
            for (int ky = 0; ky < 3; ++ky) {
#pragma unroll
                for (int kx = 0; kx < 3; ++kx) {
                    const float4 k4 =
                        *reinterpret_cast<const float4*>(kmc + (size_t)(ky * 3 + kx) * HW);
                    acc[o].x = fmaf(r[ky][kx + 0], k4.x, acc[o].x);
                    acc[o].y = fmaf(r[ky][kx + 1], k4.y, acc[o].y);
                    acc[o].z = fmaf(r[ky][kx + 2], k4.z, acc[o].z);
                    acc[o].w = fmaf(r[ky][kx + 3], k4.w, acc[o].w);
                }
            }
        }
    }

#pragma unroll
    for (int o = 0; o < OUTC; ++o) {
        *reinterpret_cast<float4*>(outb + (size_t)o * HW + (size_t)h * W + w0) = acc[o];
    }
}

extern "C" void kernel_launch(void* const* d_in, const int* in_sizes, int n_in,
                              void* d_out, int out_size, void* d_ws, size_t ws_size,
                              hipStream_t stream) {
    const float* feat = (const float*)d_in[0];
    const float* km   = (const float*)d_in[1];
    float* out        = (float*)d_out;

    const int B = 4, H = 512, W = 512;
    const int total  = B * H * (W >> 2);
    const int block  = 256;
    const int grid   = (total + block - 1) / block;
    supersample_kernel<<<grid, block, 0, stream>>>(feat, km, out, B, H, W);
}

// Round 2
// 145.923 us; speedup vs baseline: 1.8998x; 1.8998x over previous
//
#include <hip/hip_runtime.h>

#define KS 3
#define OUTC 3
#define FEATC 6
#define PATCH (FEATC * KS * KS)  // 54

typedef float f32x4 __attribute__((ext_vector_type(4)));

// out[b,o,h,w] = sum_{c,dy,dx} feat[b,c,h+dy-1,w+dx-1] * km[b, o*54 + c*9 + dy*3 + dx, h, w]
//
// One thread computes 4 consecutive pixels (w0..w0+3) for ONE output channel o.
// vs R1: o is split across threads (3x thread count -> 3072 blocks, ~2x resident
// waves, 1/3 the per-thread load count) to raise memory-level parallelism.
// km is streamed with non-temporal float4 loads (read exactly once, keep it
// out of L2 so feat stays cached); feat re-reads (x3 now) hit L2/L3 (25 MB).
__global__ __launch_bounds__(256) void supersample_kernel(
    const float* __restrict__ feat,
    const float* __restrict__ km,
    float* __restrict__ out,
    int B, int H, int W)
{
    const int Wq = W >> 2;
    const int total = B * OUTC * H * Wq;
    int idx = blockIdx.x * blockDim.x + threadIdx.x;
    if (idx >= total) return;

    // idx = ((b*OUTC + o)*H + h)*Wq + wq   (o slow so waves are o-uniform and
    // km loads stay coalesced; consecutive blocks stream contiguous km)
    const int wq = idx % Wq;
    int t = idx / Wq;
    const int h = t % H;  t /= H;
    const int o = t % OUTC;
    const int b = t / OUTC;
    const int w0 = wq << 2;

    const size_t HW = (size_t)H * (size_t)W;
    const float* featb = feat + (size_t)b * FEATC * HW;
    const float* kmo   = km   + ((size_t)b * OUTC + o) * PATCH * HW
                               + (size_t)h * W + w0;      // + c*9*HW + (ky*3+kx)*HW
    float*       outp  = out  + ((size_t)b * OUTC + o) * HW + (size_t)h * W + w0;

    f32x4 acc = (f32x4)0.f;

#pragma unroll
    for (int c = 0; c < FEATC; ++c) {
        // feat window r[ky][j] = feat[c, h+ky-1, w0-1+j], zero-padded
        float r[3][6];
#pragma unroll
        for (int ky = 0; ky < 3; ++ky) {
            const int hy = h + ky - 1;
            if (hy < 0 || hy >= H) {
#pragma unroll
                for (int j = 0; j < 6; ++j) r[ky][j] = 0.f;
            } else {
                const float* row = featb + (size_t)c * HW + (size_t)hy * W;
                const f32x4 mid = *reinterpret_cast<const f32x4*>(row + w0);  // aligned
                r[ky][1] = mid.x; r[ky][2] = mid.y; r[ky][3] = mid.z; r[ky][4] = mid.w;
                r[ky][0] = (w0 > 0)     ? row[w0 - 1] : 0.f;
                r[ky][5] = (w0 + 4 < W) ? row[w0 + 4] : 0.f;
            }
        }

        // 9 non-temporal, fully-coalesced km loads for this (o, c)
        const float* kmc = kmo + (size_t)(c * KS * KS) * HW;
        f32x4 k4[9];
#pragma unroll
        for (int t9 = 0; t9 < 9; ++t9) {
            k4[t9] = __builtin_nontemporal_load(
                reinterpret_cast<const f32x4*>(kmc + (size_t)t9 * HW));
        }
#pragma unroll
        for (int ky = 0; ky < 3; ++ky) {
#pragma unroll
            for (int kx = 0; kx < 3; ++kx) {
                const f32x4 k = k4[ky * 3 + kx];
                acc.x = fmaf(r[ky][kx + 0], k.x, acc.x);
                acc.y = fmaf(r[ky][kx + 1], k.y, acc.y);
                acc.z = fmaf(r[ky][kx + 2], k.z, acc.z);
                acc.w = fmaf(r[ky][kx + 3], k.w, acc.w);
            }
        }
    }

    *reinterpret_cast<f32x4*>(outp) = acc;
}

extern "C" void kernel_launch(void* const* d_in, const int* in_sizes, int n_in,
                              void* d_out, int out_size, void* d_ws, size_t ws_size,
                              hipStream_t stream) {
    const float* feat = (const float*)d_in[0];
    const float* km   = (const float*)d_in[1];
    float* out        = (float*)d_out;

    const int B = 4, H = 512, W = 512;
    const int total = B * OUTC * H * (W >> 2);
    const int block = 256;
    const int grid  = (total + block - 1) / block;
    supersample_kernel<<<grid, block, 0, stream>>>(feat, km, out, B, H, W);
}